// Round 15
// baseline (378.117 us; speedup 1.0000x reference)
//
#include <hip/hip_runtime.h>
#include <hip/hip_bf16.h>

// GRU scan with sparse resets. T=1024, B=256, D=128, H=128.
// Round 15: fused kernel (round 14) + two schedule upgrades:
// (1) produce DISTRIBUTED: 2 produce MFMAs per step (steps 0-11 of each
//     16-step block), placed between the hf ds_read issue and the first
//     hf-dependent MFMA -> they execute inside the ~120-cyc post-barrier
//     LDS-latency window instead of as a separate 24-MFMA lump.
//     acp/xf persist across steps (statically indexed); gil store at
//     step 11 (barrier before first consume at step 12); PCVT+PINIT for
//     the next block at step 15; LOADX at step 1 (14-step lead).
// (2) gate-chain order r -> n -> z: n retires mid-step so the e2 chain
//     overlaps z-MFMA issue; only the z-sigmoid + 1 fma trail the last MFMA.
// Everything else = round 14: 256 blocks x 256 thr (4 waves, 1/SIMD),
// zero-C scan inits, q-split roles, rst shifted in LDS read as int4,
// BARL lgkmcnt-only barrier, gi consume = ds_read_b64 prefetched 4 ahead.

#define T_STEPS 1024
#define B_SZ 256
#define D_SZ 128
#define H_SZ 128

#define SC_RZ 1.44269504f   // 1/ln2
#define SC_N  2.88539008f   // 2/ln2

typedef _Float16 f16x4 __attribute__((ext_vector_type(4)));
typedef _Float16 f16x8 __attribute__((ext_vector_type(8)));
typedef float f32x4 __attribute__((ext_vector_type(4)));

__device__ __forceinline__ float fastrcp(float x) {
#if __has_builtin(__builtin_amdgcn_rcpf)
  return __builtin_amdgcn_rcpf(x);
#else
  return 1.0f / x;
#endif
}

__device__ __forceinline__ float fexp2(float x) {
#if __has_builtin(__builtin_amdgcn_exp2f)
  return __builtin_amdgcn_exp2f(x);
#else
  return __builtin_exp2f(x);
#endif
}

// LDS-only barrier: don't drain vmcnt (ys stores / x prefetch keep flowing)
#define BARL() asm volatile("s_waitcnt lgkmcnt(0)\n\ts_barrier" ::: "memory")

// issue 8 float4 loads of x[TT + s] k-slice q*8.. into ya (fire & forget)
#define LOADX(TT_) { \
    int tl_ = (TT_) + s; if (tl_ > T_STEPS - 1) tl_ = T_STEPS - 1; \
    const float* xp_ = &seq[((size_t)tl_ * B_SZ + b) * D_SZ + q * 8]; \
    ya[0] = *(const float4*)(xp_ + 0);   ya[1] = *(const float4*)(xp_ + 4); \
    ya[2] = *(const float4*)(xp_ + 32);  ya[3] = *(const float4*)(xp_ + 36); \
    ya[4] = *(const float4*)(xp_ + 64);  ya[5] = *(const float4*)(xp_ + 68); \
    ya[6] = *(const float4*)(xp_ + 96);  ya[7] = *(const float4*)(xp_ + 100); }

// convert ya (f32) -> xf (f16 A-frags) for the produce MFMAs
#define PCVT() { \
    _Pragma("unroll") for (int kk_ = 0; kk_ < 4; kk_++) { \
      f16x8 f_; \
      f_[0] = (_Float16)ya[2*kk_].x;   f_[1] = (_Float16)ya[2*kk_].y; \
      f_[2] = (_Float16)ya[2*kk_].z;   f_[3] = (_Float16)ya[2*kk_].w; \
      f_[4] = (_Float16)ya[2*kk_+1].x; f_[5] = (_Float16)ya[2*kk_+1].y; \
      f_[6] = (_Float16)ya[2*kk_+1].z; f_[7] = (_Float16)ya[2*kk_+1].w; \
      xf[kk_] = f_; } }

// init produce accumulators with pre-scaled bias (r,z); n gets 0
#define PINIT() { \
    _Pragma("unroll") for (int g3_ = 0; g3_ < 3; g3_++) \
    _Pragma("unroll") for (int c2_ = 0; c2_ < 2; c2_++) { \
      const float bv_ = (g3_ == 2) ? 0.f : biasS[g3_][c2_]; \
      acp[g3_][c2_] = (f32x4){bv_, bv_, bv_, bv_}; } }

// one produce MFMA, linear index M_ = kk*6 + g3*2 + c2 (all compile-time)
#define PM(M_) \
    acp[((M_) % 6) >> 1][(M_) & 1] = __builtin_amdgcn_mfma_f32_16x16x32_f16( \
        xf[(M_) / 6], wiF[((M_) % 6) >> 1][(M_) & 1][(M_) / 6], \
        acp[((M_) % 6) >> 1][(M_) & 1], 0, 0, 0);

// pack + store the finished produce block into gil[PD_]
#define PSTORE(PD_) { \
    _Pragma("unroll") for (int c2_ = 0; c2_ < 2; c2_++) \
    _Pragma("unroll") for (int j_ = 0; j_ < 4; j_++) { \
      f16x4 pv_; \
      pv_[0] = (_Float16)acp[0][c2_][j_]; \
      pv_[1] = (_Float16)acp[1][c2_][j_]; \
      pv_[2] = (_Float16)acp[2][c2_][j_]; \
      pv_[3] = (_Float16)0.f; \
      *(f16x4*)&gil[PD_][q * 4 + j_][w * 32 + c2_ * 16 + s][0] = pv_; } }

// one scan step; __VA_ARGS__ = produce work placed in the hf-load shadow
#define STEPF(T_, G_, RN_, PP_, ...) { \
    const int p_ = (T_) & 1; \
    f16x8 hf0_ = *(const f16x8*)&ht[p_][ 0 + q * 8]; \
    f16x8 hf1_ = *(const f16x8*)&ht[p_][32 + q * 8]; \
    f16x8 hf2_ = *(const f16x8*)&ht[p_][64 + q * 8]; \
    f16x8 hf3_ = *(const f16x8*)&ht[p_][96 + q * 8]; \
    const float gr_ = (float)G_[0], gz_ = (float)G_[1], gn_ = (float)G_[2]; \
    G_ = *(const f16x4*)&gil[PP_][((T_) + 4) & 15][cq][0]; \
    __VA_ARGS__ \
    /* R chains (retire earliest) */ \
    f32x4 aR0_ = __builtin_amdgcn_mfma_f32_16x16x32_f16(hf0_, whF[0][0][0], Z4, 0, 0, 0); \
    f32x4 aR1_ = __builtin_amdgcn_mfma_f32_16x16x32_f16(hf0_, whF[0][1][0], Z4, 0, 0, 0); \
    aR0_ = __builtin_amdgcn_mfma_f32_16x16x32_f16(hf1_, whF[0][0][1], aR0_, 0, 0, 0); \
    aR1_ = __builtin_amdgcn_mfma_f32_16x16x32_f16(hf1_, whF[0][1][1], aR1_, 0, 0, 0); \
    aR0_ = __builtin_amdgcn_mfma_f32_16x16x32_f16(hf2_, whF[0][0][2], aR0_, 0, 0, 0); \
    aR1_ = __builtin_amdgcn_mfma_f32_16x16x32_f16(hf2_, whF[0][1][2], aR1_, 0, 0, 0); \
    aR0_ = __builtin_amdgcn_mfma_f32_16x16x32_f16(hf3_, whF[0][0][3], aR0_, 0, 0, 0); \
    aR1_ = __builtin_amdgcn_mfma_f32_16x16x32_f16(hf3_, whF[0][1][3], aR1_, 0, 0, 0); \
    /* N chains (retire mid: e2 chain overlaps Z issue) */ \
    f32x4 aN0_ = __builtin_amdgcn_mfma_f32_16x16x32_f16(hf0_, whF[2][0][0], Z4, 0, 0, 0); \
    f32x4 aN1_ = __builtin_amdgcn_mfma_f32_16x16x32_f16(hf0_, whF[2][1][0], Z4, 0, 0, 0); \
    aN0_ = __builtin_amdgcn_mfma_f32_16x16x32_f16(hf1_, whF[2][0][1], aN0_, 0, 0, 0); \
    aN1_ = __builtin_amdgcn_mfma_f32_16x16x32_f16(hf1_, whF[2][1][1], aN1_, 0, 0, 0); \
    aN0_ = __builtin_amdgcn_mfma_f32_16x16x32_f16(hf2_, whF[2][0][2], aN0_, 0, 0, 0); \
    aN1_ = __builtin_amdgcn_mfma_f32_16x16x32_f16(hf2_, whF[2][1][2], aN1_, 0, 0, 0); \
    aN0_ = __builtin_amdgcn_mfma_f32_16x16x32_f16(hf3_, whF[2][0][3], aN0_, 0, 0, 0); \
    aN1_ = __builtin_amdgcn_mfma_f32_16x16x32_f16(hf3_, whF[2][1][3], aN1_, 0, 0, 0); \
    /* Z chains last (only z-sigmoid + fma trail the final MFMA) */ \
    f32x4 aZ0_ = __builtin_amdgcn_mfma_f32_16x16x32_f16(hf0_, whF[1][0][0], Z4, 0, 0, 0); \
    f32x4 aZ1_ = __builtin_amdgcn_mfma_f32_16x16x32_f16(hf0_, whF[1][1][0], Z4, 0, 0, 0); \
    aZ0_ = __builtin_amdgcn_mfma_f32_16x16x32_f16(hf1_, whF[1][0][1], aZ0_, 0, 0, 0); \
    aZ1_ = __builtin_amdgcn_mfma_f32_16x16x32_f16(hf1_, whF[1][1][1], aZ1_, 0, 0, 0); \
    aZ0_ = __builtin_amdgcn_mfma_f32_16x16x32_f16(hf2_, whF[1][0][2], aZ0_, 0, 0, 0); \
    aZ1_ = __builtin_amdgcn_mfma_f32_16x16x32_f16(hf2_, whF[1][1][2], aZ1_, 0, 0, 0); \
    aZ0_ = __builtin_amdgcn_mfma_f32_16x16x32_f16(hf3_, whF[1][0][3], aZ0_, 0, 0, 0); \
    aZ1_ = __builtin_amdgcn_mfma_f32_16x16x32_f16(hf3_, whF[1][1][3], aZ1_, 0, 0, 0); \
    const float sR_ = (cg ? aR1_[0] : aR0_[0]) + gr_; \
    const float r_ = fastrcp(1.f + fexp2(-sR_)); \
    const float sN_ = (cg ? aN1_[0] : aN0_[0]) + bh_n; \
    const float e2_ = fexp2(gn_ + r_ * sN_); \
    const float n_ = 1.f - 2.f * fastrcp(e2_ + 1.f); \
    const float sZ_ = (cg ? aZ1_[0] : aZ0_[0]) + gz_; \
    const float z_ = fastrcp(1.f + fexp2(-sZ_)); \
    const float hnew_ = n_ + z_ * (hu - n_); \
    hu = (RN_) ? h0c : hnew_; \
    if (wrH) ht[p_ ^ 1][cq] = (_Float16)hu; \
    else ys[((size_t)(T_) * B_SZ + b) * H_SZ + cq] = hnew_; \
    yfin = hnew_; \
    BARL(); }

__global__ __launch_bounds__(256, 1)
void gru_fused2(const float* __restrict__ seq,
                const int* __restrict__ resets,
                const float* __restrict__ h0,
                const float* __restrict__ Wi,
                const float* __restrict__ Wh,
                const float* __restrict__ bh,
                float* __restrict__ out) {
  const int b = blockIdx.x;
  const int tid = threadIdx.x;
  const int w = tid >> 6;          // wave 0..3: cols [w*32, w*32+32)
  const int lane = tid & 63;
  const int q = lane >> 4;         // A k-group / C row-group / role
  const int s = lane & 15;         // A row (timestep in produce) / B,C col
  const int cg = q >> 1;           // which 16-col tile this lane owns
  const int cq = w * 32 + (cg << 4) + s;  // this lane's hidden column
  const bool wrH = ((q & 1) == 0); // role: ht writeback vs ys store

  __shared__ int rsts[T_STEPS];                        // 4 KB, SHIFTED by 1
  __shared__ __align__(16) _Float16 ht[2][H_SZ];       // 512 B
  __shared__ __align__(16) _Float16 gil[2][16][132][4];// 33 KB, {r,z,n,_}

  for (int i = tid; i < T_STEPS; i += 256)
    rsts[i] = (i < T_STEPS - 1) ? resets[(size_t)(i + 1) * B_SZ + b] : 0;

  // weight B-frags (pre-scaled): gate g3, coltile c2 -> col g3*128 + w*32 +
  // c2*16 + s; k = kk*32 + q*8 + e.  whF: scan (Wh), wiF: produce (Wi).
  f16x8 whF[3][2][4], wiF[3][2][4];
  float biasS[2][2];
#pragma unroll
  for (int g3 = 0; g3 < 3; g3++) {
    const float sc = (g3 == 2) ? SC_N : SC_RZ;
#pragma unroll
    for (int c2 = 0; c2 < 2; c2++) {
      const int col = g3 * H_SZ + w * 32 + c2 * 16 + s;
      if (g3 < 2) biasS[g3][c2] = SC_RZ * bh[col];
#pragma unroll
      for (int kk = 0; kk < 4; kk++) {
        f16x8 fh, fi;
#pragma unroll
        for (int e = 0; e < 8; e++) {
          const size_t ko = (size_t)(kk * 32 + q * 8 + e) * 384 + col;
          fh[e] = (_Float16)(sc * Wh[ko]);
          fi[e] = (_Float16)(sc * Wi[ko]);
        }
        whF[g3][c2][kk] = fh;
        wiF[g3][c2][kk] = fi;
      }
    }
  }

  const f32x4 Z4 = {0.f, 0.f, 0.f, 0.f};
  const float bh_n = SC_N * bh[2 * H_SZ + cq];
  const float h0c = h0[(size_t)b * H_SZ + cq];
  float hu = h0c;
  float yfin = h0c;

  if (tid < H_SZ) ht[0][tid] = (_Float16)h0[(size_t)b * H_SZ + tid];

  // persistent produce state (statically indexed registers)
  float4 ya[8];
  f16x8 xf[4];
  f32x4 acp[3][2];

  // prologue: produce gil[0] (steps 0..15) lumped; prep xf for block 0
  LOADX(0)
  PCVT()
  PINIT()
  PM(0)  PM(1)  PM(2)  PM(3)  PM(4)  PM(5)  PM(6)  PM(7)
  PM(8)  PM(9)  PM(10) PM(11) PM(12) PM(13) PM(14) PM(15)
  PM(16) PM(17) PM(18) PM(19) PM(20) PM(21) PM(22) PM(23)
  PSTORE(0)
  LOADX(16)
  PCVT()    // xf = x[16..31] for block 0's distributed produce
  PINIT()
  __syncthreads();

  f16x4 gA = *(const f16x4*)&gil[0][0][cq][0];
  f16x4 gB = *(const f16x4*)&gil[0][1][cq][0];
  f16x4 gC = *(const f16x4*)&gil[0][2][cq][0];
  f16x4 gD = *(const f16x4*)&gil[0][3][cq][0];

  float* ys = out + (size_t)B_SZ * H_SZ;  // out = [final_carry] ++ [ys]

#pragma unroll 1
  for (int T0 = 0; T0 < T_STEPS; T0 += 16) {
    const int par = (T0 >> 4) & 1;
    const int parx = par ^ 1;
    const int4 r0 = *(const int4*)&rsts[T0];
    const int4 r1 = *(const int4*)&rsts[T0 + 4];
    const int4 r2 = *(const int4*)&rsts[T0 + 8];
    const int4 r3 = *(const int4*)&rsts[T0 + 12];
    STEPF(T0 + 0,  gA, r0.x, par,  PM(0)  PM(1))
    STEPF(T0 + 1,  gB, r0.y, par,  PM(2)  PM(3)  LOADX(T0 + 32))
    STEPF(T0 + 2,  gC, r0.z, par,  PM(4)  PM(5))
    STEPF(T0 + 3,  gD, r0.w, par,  PM(6)  PM(7))
    STEPF(T0 + 4,  gA, r1.x, par,  PM(8)  PM(9))
    STEPF(T0 + 5,  gB, r1.y, par,  PM(10) PM(11))
    STEPF(T0 + 6,  gC, r1.z, par,  PM(12) PM(13))
    STEPF(T0 + 7,  gD, r1.w, par,  PM(14) PM(15))
    STEPF(T0 + 8,  gA, r2.x, par,  PM(16) PM(17))
    STEPF(T0 + 9,  gB, r2.y, par,  PM(18) PM(19))
    STEPF(T0 + 10, gC, r2.z, par,  PM(20) PM(21))
    STEPF(T0 + 11, gD, r2.w, par,  PM(22) PM(23) PSTORE(parx))
    STEPF(T0 + 12, gA, r3.x, parx, ;)
    STEPF(T0 + 13, gB, r3.y, parx, ;)
    STEPF(T0 + 14, gC, r3.z, parx, ;)
    STEPF(T0 + 15, gD, r3.w, parx, PCVT() PINIT())
  }
  if (wrH) out[(size_t)b * H_SZ + cq] = yfin;  // final carry = hnew(1023)
}

extern "C" void kernel_launch(void* const* d_in, const int* in_sizes, int n_in,
                              void* d_out, int out_size, void* d_ws, size_t ws_size,
                              hipStream_t stream) {
  const float* seq    = (const float*)d_in[0];
  const int*   resets = (const int*)d_in[1];
  const float* h0     = (const float*)d_in[2];
  const float* Wi     = (const float*)d_in[3];
  const float* Wh     = (const float*)d_in[4];
  const float* bh     = (const float*)d_in[5];
  (void)in_sizes; (void)n_in; (void)out_size; (void)d_ws; (void)ws_size;

  gru_fused2<<<B_SZ, 256, 0, stream>>>(seq, resets, h0, Wi, Wh, bh,
                                       (float*)d_out);
}

// Round 16
// 374.908 us; speedup vs baseline: 1.0086x; 1.0086x over previous
//
#include <hip/hip_runtime.h>
#include <hip/hip_bf16.h>

// GRU scan with sparse resets. T=1024, B=256, D=128, H=128.
// Round 16: round-14 structure (best: 372.6us) restored, ONE change:
// gate-chain order z -> r -> n with fma-form blend.
//   - Z MFMA chains issue FIRST (retire ~slot 8): sigma(z), z*hu, (1-z)
//     all compute on the VALU under the R/N issue window.
//   - R chains second: sigma(r) computes under N issue.
//   - N chains LAST: post-retire serial tail is only
//     {sel, +bh_n, fma(gn + r*sN), exp2, +1, rcp, n-fma, hnew-fma}.
//   hnew = fma(n, 1-z, z*hu)  ==  n + z*(hu - n)  (identical math).
// Everything else = round 14: single fused kernel, 256 blocks x 256 thr
// (4 waves, 1/SIMD); produce gi = x[T0+16..31] @ Wi once per 16 steps in
// the otherwise-wasted MFMA M-rows (lumped, double-buffered gil in LDS);
// zero-C scan inits; q-split roles (ht writeback vs ys store); rst
// shifted in LDS read as int4; BARL lgkmcnt-only barrier; gi consume =
// one ds_read_b64 prefetched 4 steps ahead; x loaded 16 steps ahead.

#define T_STEPS 1024
#define B_SZ 256
#define D_SZ 128
#define H_SZ 128

#define SC_RZ 1.44269504f   // 1/ln2
#define SC_N  2.88539008f   // 2/ln2

typedef _Float16 f16x4 __attribute__((ext_vector_type(4)));
typedef _Float16 f16x8 __attribute__((ext_vector_type(8)));
typedef float f32x4 __attribute__((ext_vector_type(4)));

__device__ __forceinline__ float fastrcp(float x) {
#if __has_builtin(__builtin_amdgcn_rcpf)
  return __builtin_amdgcn_rcpf(x);
#else
  return 1.0f / x;
#endif
}

__device__ __forceinline__ float fexp2(float x) {
#if __has_builtin(__builtin_amdgcn_exp2f)
  return __builtin_amdgcn_exp2f(x);
#else
  return __builtin_exp2f(x);
#endif
}

// LDS-only barrier: don't drain vmcnt (ys stores / x prefetch keep flowing)
#define BARL() asm volatile("s_waitcnt lgkmcnt(0)\n\ts_barrier" ::: "memory")

// issue 8 float4 loads of x[TT + s] k-slice q*8.. (fire & forget, 16-step lead)
#define LOADX(TT_, Y_) { \
    int tl_ = (TT_) + s; if (tl_ > T_STEPS - 1) tl_ = T_STEPS - 1; \
    const float* xp_ = &seq[((size_t)tl_ * B_SZ + b) * D_SZ + q * 8]; \
    Y_[0] = *(const float4*)(xp_ + 0);   Y_[1] = *(const float4*)(xp_ + 4); \
    Y_[2] = *(const float4*)(xp_ + 32);  Y_[3] = *(const float4*)(xp_ + 36); \
    Y_[4] = *(const float4*)(xp_ + 64);  Y_[5] = *(const float4*)(xp_ + 68); \
    Y_[6] = *(const float4*)(xp_ + 96);  Y_[7] = *(const float4*)(xp_ + 100); }

// produce gi block (16 timesteps = MFMA rows) into gil[PD_]
#define PRODUCE(PD_, Y_) { \
    f16x8 xf_[4]; \
    _Pragma("unroll") for (int kk_ = 0; kk_ < 4; kk_++) { \
      f16x8 f_; \
      f_[0] = (_Float16)Y_[2*kk_].x;   f_[1] = (_Float16)Y_[2*kk_].y; \
      f_[2] = (_Float16)Y_[2*kk_].z;   f_[3] = (_Float16)Y_[2*kk_].w; \
      f_[4] = (_Float16)Y_[2*kk_+1].x; f_[5] = (_Float16)Y_[2*kk_+1].y; \
      f_[6] = (_Float16)Y_[2*kk_+1].z; f_[7] = (_Float16)Y_[2*kk_+1].w; \
      xf_[kk_] = f_; } \
    f32x4 ac_[3][2]; \
    _Pragma("unroll") for (int g3_ = 0; g3_ < 3; g3_++) \
      _Pragma("unroll") for (int c2_ = 0; c2_ < 2; c2_++) { \
        const float bv_ = (g3_ == 2) ? 0.f : biasS[g3_][c2_]; \
        ac_[g3_][c2_] = (f32x4){bv_, bv_, bv_, bv_}; } \
    _Pragma("unroll") for (int kk_ = 0; kk_ < 4; kk_++) \
      _Pragma("unroll") for (int g3_ = 0; g3_ < 3; g3_++) \
        _Pragma("unroll") for (int c2_ = 0; c2_ < 2; c2_++) \
          ac_[g3_][c2_] = __builtin_amdgcn_mfma_f32_16x16x32_f16( \
              xf_[kk_], wiF[g3_][c2_][kk_], ac_[g3_][c2_], 0, 0, 0); \
    _Pragma("unroll") for (int c2_ = 0; c2_ < 2; c2_++) \
      _Pragma("unroll") for (int j_ = 0; j_ < 4; j_++) { \
        f16x4 pv_; \
        pv_[0] = (_Float16)ac_[0][c2_][j_]; \
        pv_[1] = (_Float16)ac_[1][c2_][j_]; \
        pv_[2] = (_Float16)ac_[2][c2_][j_]; \
        pv_[3] = (_Float16)0.f; \
        *(f16x4*)&gil[PD_][q * 4 + j_][w * 32 + c2_ * 16 + s][0] = pv_; } }

// one scan step: G_ = f16x4 {r,z,n,_} for this lane's column (consumed),
// refilled from gil[PP_] row (T_+4)&15. MFMA order: Z -> R -> N.
#define STEPF(T_, G_, RN_, PP_) { \
    const int p_ = (T_) & 1; \
    f16x8 hf0_ = *(const f16x8*)&ht[p_][ 0 + q * 8]; \
    f16x8 hf1_ = *(const f16x8*)&ht[p_][32 + q * 8]; \
    f16x8 hf2_ = *(const f16x8*)&ht[p_][64 + q * 8]; \
    f16x8 hf3_ = *(const f16x8*)&ht[p_][96 + q * 8]; \
    const float gr_ = (float)G_[0], gz_ = (float)G_[1], gn_ = (float)G_[2]; \
    G_ = *(const f16x4*)&gil[PP_][((T_) + 4) & 15][cq][0]; \
    /* Z chains first: retire earliest, sigma(z)/z*hu/(1-z) overlap R,N */ \
    f32x4 aZ0_ = __builtin_amdgcn_mfma_f32_16x16x32_f16(hf0_, whF[1][0][0], Z4, 0, 0, 0); \
    f32x4 aZ1_ = __builtin_amdgcn_mfma_f32_16x16x32_f16(hf0_, whF[1][1][0], Z4, 0, 0, 0); \
    aZ0_ = __builtin_amdgcn_mfma_f32_16x16x32_f16(hf1_, whF[1][0][1], aZ0_, 0, 0, 0); \
    aZ1_ = __builtin_amdgcn_mfma_f32_16x16x32_f16(hf1_, whF[1][1][1], aZ1_, 0, 0, 0); \
    aZ0_ = __builtin_amdgcn_mfma_f32_16x16x32_f16(hf2_, whF[1][0][2], aZ0_, 0, 0, 0); \
    aZ1_ = __builtin_amdgcn_mfma_f32_16x16x32_f16(hf2_, whF[1][1][2], aZ1_, 0, 0, 0); \
    aZ0_ = __builtin_amdgcn_mfma_f32_16x16x32_f16(hf3_, whF[1][0][3], aZ0_, 0, 0, 0); \
    aZ1_ = __builtin_amdgcn_mfma_f32_16x16x32_f16(hf3_, whF[1][1][3], aZ1_, 0, 0, 0); \
    /* R chains second: sigma(r) overlaps N issue */ \
    f32x4 aR0_ = __builtin_amdgcn_mfma_f32_16x16x32_f16(hf0_, whF[0][0][0], Z4, 0, 0, 0); \
    f32x4 aR1_ = __builtin_amdgcn_mfma_f32_16x16x32_f16(hf0_, whF[0][1][0], Z4, 0, 0, 0); \
    aR0_ = __builtin_amdgcn_mfma_f32_16x16x32_f16(hf1_, whF[0][0][1], aR0_, 0, 0, 0); \
    aR1_ = __builtin_amdgcn_mfma_f32_16x16x32_f16(hf1_, whF[0][1][1], aR1_, 0, 0, 0); \
    aR0_ = __builtin_amdgcn_mfma_f32_16x16x32_f16(hf2_, whF[0][0][2], aR0_, 0, 0, 0); \
    aR1_ = __builtin_amdgcn_mfma_f32_16x16x32_f16(hf2_, whF[0][1][2], aR1_, 0, 0, 0); \
    aR0_ = __builtin_amdgcn_mfma_f32_16x16x32_f16(hf3_, whF[0][0][3], aR0_, 0, 0, 0); \
    aR1_ = __builtin_amdgcn_mfma_f32_16x16x32_f16(hf3_, whF[0][1][3], aR1_, 0, 0, 0); \
    /* N chains last: minimal post-retire tail */ \
    f32x4 aN0_ = __builtin_amdgcn_mfma_f32_16x16x32_f16(hf0_, whF[2][0][0], Z4, 0, 0, 0); \
    f32x4 aN1_ = __builtin_amdgcn_mfma_f32_16x16x32_f16(hf0_, whF[2][1][0], Z4, 0, 0, 0); \
    aN0_ = __builtin_amdgcn_mfma_f32_16x16x32_f16(hf1_, whF[2][0][1], aN0_, 0, 0, 0); \
    aN1_ = __builtin_amdgcn_mfma_f32_16x16x32_f16(hf1_, whF[2][1][1], aN1_, 0, 0, 0); \
    aN0_ = __builtin_amdgcn_mfma_f32_16x16x32_f16(hf2_, whF[2][0][2], aN0_, 0, 0, 0); \
    aN1_ = __builtin_amdgcn_mfma_f32_16x16x32_f16(hf2_, whF[2][1][2], aN1_, 0, 0, 0); \
    aN0_ = __builtin_amdgcn_mfma_f32_16x16x32_f16(hf3_, whF[2][0][3], aN0_, 0, 0, 0); \
    aN1_ = __builtin_amdgcn_mfma_f32_16x16x32_f16(hf3_, whF[2][1][3], aN1_, 0, 0, 0); \
    const float sZ_ = (cg ? aZ1_[0] : aZ0_[0]) + gz_; \
    const float z_ = fastrcp(1.f + fexp2(-sZ_)); \
    const float zh_ = z_ * hu; \
    const float omz_ = 1.f - z_; \
    const float sR_ = (cg ? aR1_[0] : aR0_[0]) + gr_; \
    const float r_ = fastrcp(1.f + fexp2(-sR_)); \
    const float sN_ = (cg ? aN1_[0] : aN0_[0]) + bh_n; \
    const float e2_ = fexp2(gn_ + r_ * sN_); \
    const float n_ = 1.f - 2.f * fastrcp(e2_ + 1.f); \
    const float hnew_ = fmaf(n_, omz_, zh_); \
    hu = (RN_) ? h0c : hnew_; \
    if (wrH) ht[p_ ^ 1][cq] = (_Float16)hu; \
    else ys[((size_t)(T_) * B_SZ + b) * H_SZ + cq] = hnew_; \
    yfin = hnew_; \
    BARL(); }

__global__ __launch_bounds__(256, 1)
void gru_fused3(const float* __restrict__ seq,
                const int* __restrict__ resets,
                const float* __restrict__ h0,
                const float* __restrict__ Wi,
                const float* __restrict__ Wh,
                const float* __restrict__ bh,
                float* __restrict__ out) {
  const int b = blockIdx.x;
  const int tid = threadIdx.x;
  const int w = tid >> 6;          // wave 0..3: cols [w*32, w*32+32)
  const int lane = tid & 63;
  const int q = lane >> 4;         // A k-group / C row-group / role
  const int s = lane & 15;         // A row (timestep in produce) / B,C col
  const int cg = q >> 1;           // which 16-col tile this lane owns
  const int cq = w * 32 + (cg << 4) + s;  // this lane's hidden column
  const bool wrH = ((q & 1) == 0); // role: ht writeback vs ys store

  __shared__ int rsts[T_STEPS];                        // 4 KB, SHIFTED by 1
  __shared__ __align__(16) _Float16 ht[2][H_SZ];       // 512 B
  __shared__ __align__(16) _Float16 gil[2][16][132][4];// 33 KB, {r,z,n,_}

  for (int i = tid; i < T_STEPS; i += 256)
    rsts[i] = (i < T_STEPS - 1) ? resets[(size_t)(i + 1) * B_SZ + b] : 0;

  // weight B-frags (pre-scaled): gate g3, coltile c2 -> col g3*128 + w*32 +
  // c2*16 + s; k = kk*32 + q*8 + e.  whF: scan (Wh), wiF: produce (Wi).
  f16x8 whF[3][2][4], wiF[3][2][4];
  float biasS[2][2];
#pragma unroll
  for (int g3 = 0; g3 < 3; g3++) {
    const float sc = (g3 == 2) ? SC_N : SC_RZ;
#pragma unroll
    for (int c2 = 0; c2 < 2; c2++) {
      const int col = g3 * H_SZ + w * 32 + c2 * 16 + s;
      if (g3 < 2) biasS[g3][c2] = SC_RZ * bh[col];
#pragma unroll
      for (int kk = 0; kk < 4; kk++) {
        f16x8 fh, fi;
#pragma unroll
        for (int e = 0; e < 8; e++) {
          const size_t ko = (size_t)(kk * 32 + q * 8 + e) * 384 + col;
          fh[e] = (_Float16)(sc * Wh[ko]);
          fi[e] = (_Float16)(sc * Wi[ko]);
        }
        whF[g3][c2][kk] = fh;
        wiF[g3][c2][kk] = fi;
      }
    }
  }

  const f32x4 Z4 = {0.f, 0.f, 0.f, 0.f};
  const float bh_n = SC_N * bh[2 * H_SZ + cq];
  const float h0c = h0[(size_t)b * H_SZ + cq];
  float hu = h0c;
  float yfin = h0c;

  if (tid < H_SZ) ht[0][tid] = (_Float16)h0[(size_t)b * H_SZ + tid];

  // prologue: produce gi for steps 0..15 into gil[0]; stage x for 16..31
  float4 ya[8];
  LOADX(0, ya)
  PRODUCE(0, ya)
  LOADX(16, ya)
  __syncthreads();

  f16x4 gA = *(const f16x4*)&gil[0][0][cq][0];
  f16x4 gB = *(const f16x4*)&gil[0][1][cq][0];
  f16x4 gC = *(const f16x4*)&gil[0][2][cq][0];
  f16x4 gD = *(const f16x4*)&gil[0][3][cq][0];

  float* ys = out + (size_t)B_SZ * H_SZ;  // out = [final_carry] ++ [ys]

#pragma unroll 1
  for (int T0 = 0; T0 < T_STEPS; T0 += 16) {
    const int par = (T0 >> 4) & 1;
    const int parx = par ^ 1;
    PRODUCE(parx, ya)          // gi for steps T0+16..T0+31 (barrier-covered)
    LOADX(T0 + 32, ya)         // x for the next produce (16-step lead)
    const int4 r0 = *(const int4*)&rsts[T0];
    const int4 r1 = *(const int4*)&rsts[T0 + 4];
    const int4 r2 = *(const int4*)&rsts[T0 + 8];
    const int4 r3 = *(const int4*)&rsts[T0 + 12];
    STEPF(T0 + 0,  gA, r0.x, par)
    STEPF(T0 + 1,  gB, r0.y, par)
    STEPF(T0 + 2,  gC, r0.z, par)
    STEPF(T0 + 3,  gD, r0.w, par)
    STEPF(T0 + 4,  gA, r1.x, par)
    STEPF(T0 + 5,  gB, r1.y, par)
    STEPF(T0 + 6,  gC, r1.z, par)
    STEPF(T0 + 7,  gD, r1.w, par)
    STEPF(T0 + 8,  gA, r2.x, par)
    STEPF(T0 + 9,  gB, r2.y, par)
    STEPF(T0 + 10, gC, r2.z, par)
    STEPF(T0 + 11, gD, r2.w, par)
    STEPF(T0 + 12, gA, r3.x, parx)   // prefetch rows 0..3 of next buffer
    STEPF(T0 + 13, gB, r3.y, parx)
    STEPF(T0 + 14, gC, r3.z, parx)
    STEPF(T0 + 15, gD, r3.w, parx)
  }
  if (wrH) out[(size_t)b * H_SZ + cq] = yfin;  // final carry = hnew(1023)
}

extern "C" void kernel_launch(void* const* d_in, const int* in_sizes, int n_in,
                              void* d_out, int out_size, void* d_ws, size_t ws_size,
                              hipStream_t stream) {
  const float* seq    = (const float*)d_in[0];
  const int*   resets = (const int*)d_in[1];
  const float* h0     = (const float*)d_in[2];
  const float* Wi     = (const float*)d_in[3];
  const float* Wh     = (const float*)d_in[4];
  const float* bh     = (const float*)d_in[5];
  (void)in_sizes; (void)n_in; (void)out_size; (void)d_ws; (void)ws_size;

  gru_fused3<<<B_SZ, 256, 0, stream>>>(seq, resets, h0, Wi, Wh, bh,
                                       (float*)d_out);
}